// Round 1
// baseline (368.280 us; speedup 1.0000x reference)
//
#include <hip/hip_runtime.h>
#include <hip/hip_bf16.h>
#include <math.h>

#define H_    16
#define DK_   64
#define Dm    1024
#define Bb    2
#define Ss    2048
#define Mrows 4096   // B*S

typedef short s16x8 __attribute__((ext_vector_type(8)));
typedef float f32x4 __attribute__((ext_vector_type(4)));
typedef unsigned short u16;

__device__ __forceinline__ u16 f2b(float f) {
  __hip_bfloat16 h = __float2bfloat16(f);
  return *reinterpret_cast<u16*>(&h);
}
__device__ __forceinline__ float b2f(u16 u) {
  __hip_bfloat16 h;
  *reinterpret_cast<u16*>(&h) = u;
  return __bfloat162float(h);
}

// async global->LDS, 16B per lane; LDS dest = wave-uniform base + lane*16
#define GLDS(g, l)                                                             \
  __builtin_amdgcn_global_load_lds(                                            \
      (const __attribute__((address_space(1))) unsigned int*)(g),              \
      (__attribute__((address_space(3))) unsigned int*)(l), 16, 0, 0)

// ---------------------------------------------------------------- cast fp32->bf16
__global__ __launch_bounds__(256) void k_cast(const float* __restrict__ s,
                                              u16* __restrict__ d, int n4) {
  int i = blockIdx.x * 256 + threadIdx.x;
  if (i >= n4) return;
  float4 v = reinterpret_cast<const float4*>(s)[i];
  ushort4 o;
  o.x = f2b(v.x); o.y = f2b(v.y); o.z = f2b(v.z); o.w = f2b(v.w);
  reinterpret_cast<ushort4*>(d)[i] = o;
}

// ---------------------------------------------------------------- RoPE on Q and K (bf16 in/out)
__global__ __launch_bounds__(256) void k_rope(u16* __restrict__ Q, u16* __restrict__ K,
                                              const int* __restrict__ pos) {
  int idx = blockIdx.x * 256 + threadIdx.x;      // pair index over Mrows*512
  if (idx >= Mrows * (Dm / 2)) return;
  int row = idx >> 9;      // /512 pairs per row
  int pc  = idx & 511;
  int i   = pc & 31;       // pair index within head (d2 = 32)
  int h   = pc >> 5;
  int col = h * 64 + i * 2;
  float p   = (float)pos[row & (Ss - 1)];
  float inv = powf(10000.0f, -(float)i / 32.0f);   // THETA^(-2i/64)
  float ang = p * inv;
  float sn = sinf(ang), cs = cosf(ang);
  size_t o = (size_t)row * Dm + col;
  {
    float xe = b2f(Q[o]), xo = b2f(Q[o + 1]);
    Q[o]     = f2b(cs * xe - sn * xo);
    Q[o + 1] = f2b(sn * xe + cs * xo);
  }
  {
    float xe = b2f(K[o]), xo = b2f(K[o + 1]);
    K[o]     = f2b(cs * xe - sn * xo);
    K[o + 1] = f2b(sn * xe + cs * xo);
  }
}

// ---------------------------------------------------------------- C = A * B^T (bf16 in, bf16/f32 out)
// 128x128 tile, BK=32, 256 threads = 4 waves in 2x2, each wave 64x64 (4x4 frags)
__global__ __launch_bounds__(256) void k_gemm_bt(
    const u16* __restrict__ A,
    const u16* __restrict__ B0, const u16* __restrict__ B1, const u16* __restrict__ B2,
    u16* __restrict__ O0, u16* __restrict__ O1, u16* __restrict__ O2,
    float* __restrict__ OF, int M, int N, int K, int f32out) {
  __shared__ __align__(16) u16 lsA[128 * 32];
  __shared__ __align__(16) u16 lsB[128 * 32];
  const int tid = threadIdx.x, lane = tid & 63, wave = tid >> 6;
  const int quad = lane >> 4, l16 = lane & 15;
  const int wrow = wave >> 1, wcol = wave & 1;
  const int m0 = blockIdx.x * 128, n0 = blockIdx.y * 128;
  const int z = blockIdx.z;
  const u16* Bp = (z == 0) ? B0 : (z == 1) ? B1 : B2;
  u16* Op = (z == 0) ? O0 : (z == 1) ? O1 : O2;
  f32x4 acc[4][4] = {};
  const int c0 = wave * 2;

  for (int k0 = 0; k0 < K; k0 += 32) {
#pragma unroll
    for (int c = 0; c < 2; ++c) {
      int f = (c0 + c) * 512 + lane * 8;   // flat bf16 index in 128x32 tile
      int row = f >> 5, colk = f & 31;
      GLDS(A  + (size_t)(m0 + row) * K + k0 + colk, lsA + (c0 + c) * 512);
      GLDS(Bp + (size_t)(n0 + row) * K + k0 + colk, lsB + (c0 + c) * 512);
    }
    __syncthreads();
    s16x8 af[4], bfr[4];
#pragma unroll
    for (int i = 0; i < 4; ++i) {
      af[i]  = *reinterpret_cast<const s16x8*>(&lsA[(wrow * 64 + i * 16 + l16) * 32 + quad * 8]);
      bfr[i] = *reinterpret_cast<const s16x8*>(&lsB[(wcol * 64 + i * 16 + l16) * 32 + quad * 8]);
    }
#pragma unroll
    for (int mi = 0; mi < 4; ++mi)
#pragma unroll
      for (int ni = 0; ni < 4; ++ni)
        acc[mi][ni] = __builtin_amdgcn_mfma_f32_16x16x32_bf16(af[mi], bfr[ni], acc[mi][ni], 0, 0, 0);
    __syncthreads();
  }

#pragma unroll
  for (int mi = 0; mi < 4; ++mi)
#pragma unroll
    for (int ni = 0; ni < 4; ++ni)
#pragma unroll
      for (int r = 0; r < 4; ++r) {
        int row = m0 + wrow * 64 + mi * 16 + quad * 4 + r;
        int col = n0 + wcol * 64 + ni * 16 + l16;
        float v = acc[mi][ni][r];
        size_t idx = (size_t)row * N + col;
        if (f32out) OF[idx] = v;
        else        Op[idx] = f2b(v);
      }
}

// ---------------------------------------------------------------- flash attention (causal)
// block = (b, h, 64-query tile); 4 waves, wave owns 16 q rows; k-tiles of 64
__global__ __launch_bounds__(256) void k_flash(const u16* __restrict__ Q,
                                               const u16* __restrict__ K,
                                               const u16* __restrict__ V,
                                               u16* __restrict__ O) {
  __shared__ __align__(16) u16 lsK[64 * 64];       // [key][dk]
  __shared__ __align__(16) u16 lsVT[64 * 64];      // [dk][key]
  __shared__ __align__(16) u16 lsP[4][16 * 64];    // per-wave P, [qrow][key]
  const int tid = threadIdx.x, lane = tid & 63, wave = tid >> 6;
  const int quad = lane >> 4, l16 = lane & 15;
  const int h = blockIdx.y & (H_ - 1), b = blockIdx.y >> 4;
  const int q0 = blockIdx.x * 64;
  const int qrow = q0 + wave * 16;

  // Q A-frags straight from global: A[m=l16][k=quad*8+j], two 32-wide k chunks
  const size_t qoff = (size_t)(b * Ss + qrow + l16) * Dm + h * 64;
  s16x8 qf0 = *reinterpret_cast<const s16x8*>(&Q[qoff + quad * 8]);
  s16x8 qf1 = *reinterpret_cast<const s16x8*>(&Q[qoff + 32 + quad * 8]);

  f32x4 o[4] = {};
  float m_i[4], l_i[4], alpha[4];
#pragma unroll
  for (int r = 0; r < 4; ++r) { m_i[r] = -INFINITY; l_i[r] = 0.f; }
  const float scale = 0.125f;   // 1/sqrt(64)
  const int ktmax = q0 >> 6;
  const int c0 = wave * 2;

  for (int kt = 0; kt <= ktmax; ++kt) {
    const size_t kvbase = (size_t)(b * Ss + kt * 64) * Dm + h * 64;
    // stage K tile [64][64] natural via global_load_lds
#pragma unroll
    for (int c = 0; c < 2; ++c) {
      int f = (c0 + c) * 512 + lane * 8;
      int row = f >> 6, colk = f & 63;
      GLDS(K + kvbase + (size_t)row * Dm + colk, lsK + (c0 + c) * 512);
    }
    // stage V transposed: lsVT[dk][key]
#pragma unroll
    for (int it = 0; it < 2; ++it) {
      int r  = (tid >> 3) + it * 32;
      int cv = (tid & 7) * 8;
      s16x8 vv = *reinterpret_cast<const s16x8*>(&V[kvbase + (size_t)r * Dm + cv]);
#pragma unroll
      for (int j = 0; j < 8; ++j) lsVT[(cv + j) * 64 + r] = (u16)vv[j];
    }
    __syncthreads();

    // S = Q K^T : B-frag B[k=dk][n=key] = lsK[n][k] (k-contiguous)
    f32x4 s[4] = {};
#pragma unroll
    for (int ni = 0; ni < 4; ++ni) {
      s16x8 kf0 = *reinterpret_cast<const s16x8*>(&lsK[(ni * 16 + l16) * 64 + quad * 8]);
      s16x8 kf1 = *reinterpret_cast<const s16x8*>(&lsK[(ni * 16 + l16) * 64 + 32 + quad * 8]);
      s[ni] = __builtin_amdgcn_mfma_f32_16x16x32_bf16(qf0, kf0, s[ni], 0, 0, 0);
      s[ni] = __builtin_amdgcn_mfma_f32_16x16x32_bf16(qf1, kf1, s[ni], 0, 0, 0);
    }
    // causal mask on diagonal tile
    if (kt == ktmax) {
#pragma unroll
      for (int ni = 0; ni < 4; ++ni)
#pragma unroll
        for (int r = 0; r < 4; ++r) {
          int gq = qrow + quad * 4 + r;
          int gk = kt * 64 + ni * 16 + l16;
          if (gk > gq) s[ni][r] = -INFINITY;
        }
    }
#pragma unroll
    for (int ni = 0; ni < 4; ++ni) s[ni] *= scale;

    // online softmax: rows of a quad are reduced across its 16 lanes
#pragma unroll
    for (int r = 0; r < 4; ++r) {
      float mx = fmaxf(fmaxf(s[0][r], s[1][r]), fmaxf(s[2][r], s[3][r]));
#pragma unroll
      for (int off = 8; off >= 1; off >>= 1) mx = fmaxf(mx, __shfl_xor(mx, off, 16));
      float mnew = fmaxf(m_i[r], mx);
      alpha[r] = __expf(m_i[r] - mnew);
      m_i[r] = mnew;
      float rs = 0.f;
#pragma unroll
      for (int ni = 0; ni < 4; ++ni) {
        float p = __expf(s[ni][r] - mnew);
        s[ni][r] = p;
        rs += p;
      }
#pragma unroll
      for (int off = 8; off >= 1; off >>= 1) rs += __shfl_xor(rs, off, 16);
      l_i[r] = l_i[r] * alpha[r] + rs;
    }
    // rescale O, write P (C-layout -> LDS -> A-layout)
#pragma unroll
    for (int ni = 0; ni < 4; ++ni) {
#pragma unroll
      for (int r = 0; r < 4; ++r) {
        o[ni][r] *= alpha[r];
        lsP[wave][(quad * 4 + r) * 64 + ni * 16 + l16] = f2b(s[ni][r]);
      }
    }
    // O += P V : A-frag from lsP, B-frag B[k=key][n=dk] = lsVT[n][k]
#pragma unroll
    for (int kc = 0; kc < 2; ++kc) {
      s16x8 pf = *reinterpret_cast<const s16x8*>(&lsP[wave][l16 * 64 + kc * 32 + quad * 8]);
#pragma unroll
      for (int ni = 0; ni < 4; ++ni) {
        s16x8 vf = *reinterpret_cast<const s16x8*>(&lsVT[(ni * 16 + l16) * 64 + kc * 32 + quad * 8]);
        o[ni] = __builtin_amdgcn_mfma_f32_16x16x32_bf16(pf, vf, o[ni], 0, 0, 0);
      }
    }
    __syncthreads();
  }

#pragma unroll
  for (int ni = 0; ni < 4; ++ni)
#pragma unroll
    for (int r = 0; r < 4; ++r) {
      int gq = qrow + quad * 4 + r;
      int gc = h * 64 + ni * 16 + l16;
      O[(size_t)(b * Ss + gq) * Dm + gc] = f2b(o[ni][r] / l_i[r]);
    }
}

// ---------------------------------------------------------------- launch
extern "C" void kernel_launch(void* const* d_in, const int* in_sizes, int n_in,
                              void* d_out, int out_size, void* d_ws, size_t ws_size,
                              hipStream_t stream) {
  const float* x  = (const float*)d_in[0];
  const float* Wq = (const float*)d_in[1];
  const float* Wk = (const float*)d_in[2];
  const float* Wv = (const float*)d_in[3];
  const float* Wo = (const float*)d_in[4];
  const int* pos  = (const int*)d_in[5];
  float* out = (float*)d_out;

  char* w = (char*)d_ws;
  u16* xb  = (u16*)w; w += (size_t)Mrows * Dm * 2;
  u16* wqb = (u16*)w; w += (size_t)Dm * Dm * 2;
  u16* wkb = (u16*)w; w += (size_t)Dm * Dm * 2;
  u16* wvb = (u16*)w; w += (size_t)Dm * Dm * 2;
  u16* wob = (u16*)w; w += (size_t)Dm * Dm * 2;
  u16* Qb  = (u16*)w; w += (size_t)Mrows * Dm * 2;
  u16* Kb  = (u16*)w; w += (size_t)Mrows * Dm * 2;
  u16* Vb  = (u16*)w; w += (size_t)Mrows * Dm * 2;
  u16* Ab  = (u16*)w; w += (size_t)Mrows * Dm * 2;

  k_cast<<<(Mrows * Dm / 4 + 255) / 256, 256, 0, stream>>>(x, xb, Mrows * Dm / 4);
  k_cast<<<(Dm * Dm / 4 + 255) / 256, 256, 0, stream>>>(Wq, wqb, Dm * Dm / 4);
  k_cast<<<(Dm * Dm / 4 + 255) / 256, 256, 0, stream>>>(Wk, wkb, Dm * Dm / 4);
  k_cast<<<(Dm * Dm / 4 + 255) / 256, 256, 0, stream>>>(Wv, wvb, Dm * Dm / 4);
  k_cast<<<(Dm * Dm / 4 + 255) / 256, 256, 0, stream>>>(Wo, wob, Dm * Dm / 4);

  // fused QKV projections: z selects W and destination
  k_gemm_bt<<<dim3(32, 8, 3), 256, 0, stream>>>(xb, wqb, wkb, wvb,
                                                Qb, Kb, Vb, nullptr,
                                                Mrows, Dm, Dm, 0);
  k_rope<<<(Mrows * 512 + 255) / 256, 256, 0, stream>>>(Qb, Kb, pos);
  k_flash<<<dim3(Ss / 64, Bb * H_), 256, 0, stream>>>(Qb, Kb, Vb, Ab);
  // output projection, fp32 epilogue
  k_gemm_bt<<<dim3(32, 8, 1), 256, 0, stream>>>(Ab, wob, wob, wob,
                                                nullptr, nullptr, nullptr, out,
                                                Mrows, Dm, Dm, 1);
}

// Round 2
// 260.007 us; speedup vs baseline: 1.4164x; 1.4164x over previous
//
#include <hip/hip_runtime.h>
#include <hip/hip_bf16.h>
#include <math.h>

#define H_    16
#define DK_   64
#define Dm    1024
#define Bb    2
#define Ss    2048
#define Mrows 4096   // B*S

typedef short s16x8 __attribute__((ext_vector_type(8)));
typedef float f32x4 __attribute__((ext_vector_type(4)));
typedef unsigned short u16;

__device__ __forceinline__ u16 f2b(float f) {
  __hip_bfloat16 h = __float2bfloat16(f);
  return *reinterpret_cast<u16*>(&h);
}
__device__ __forceinline__ float b2f(u16 u) {
  __hip_bfloat16 h;
  *reinterpret_cast<u16*>(&h) = u;
  return __bfloat162float(h);
}

// async global->LDS, 16B per lane; LDS dest = wave-uniform base + lane*16
#define GLDS(g, l)                                                             \
  __builtin_amdgcn_global_load_lds(                                            \
      (const __attribute__((address_space(1))) unsigned int*)(g),              \
      (__attribute__((address_space(3))) unsigned int*)(l), 16, 0, 0)

// XOR-swizzled index into a [rows][64] u16 tile: spreads the 128B row stride
// (which is ≡ 0 mod 32 banks) across bank groups. 16B-chunk granular, so
// b128 reads of 8 contiguous u16 (col&7 spanning 0..7, col>>3 fixed) stay legal.
__device__ __forceinline__ int SW64(int row, int col) {
  return row * 64 + ((((col >> 3) ^ (row & 7) ^ (row >> 3)) & 7) << 3) + (col & 7);
}

// ---------------------------------------------------------------- cast fp32->bf16
__global__ __launch_bounds__(256) void k_cast(const float* __restrict__ s,
                                              u16* __restrict__ d, int n4) {
  int i = blockIdx.x * 256 + threadIdx.x;
  if (i >= n4) return;
  float4 v = reinterpret_cast<const float4*>(s)[i];
  ushort4 o;
  o.x = f2b(v.x); o.y = f2b(v.y); o.z = f2b(v.z); o.w = f2b(v.w);
  reinterpret_cast<ushort4*>(d)[i] = o;
}

// ---------------------------------------------------------------- RoPE on Q and K (bf16 in/out)
__global__ __launch_bounds__(256) void k_rope(u16* __restrict__ Q, u16* __restrict__ K,
                                              const int* __restrict__ pos) {
  int idx = blockIdx.x * 256 + threadIdx.x;      // pair index over Mrows*512
  if (idx >= Mrows * (Dm / 2)) return;
  int row = idx >> 9;
  int pc  = idx & 511;
  int i   = pc & 31;       // pair index within head (d2 = 32)
  int h   = pc >> 5;
  int col = h * 64 + i * 2;
  float p   = (float)pos[row & (Ss - 1)];
  float inv = powf(10000.0f, -(float)i / 32.0f);
  float ang = p * inv;
  float sn = sinf(ang), cs = cosf(ang);
  size_t o = (size_t)row * Dm + col;
  {
    float xe = b2f(Q[o]), xo = b2f(Q[o + 1]);
    Q[o]     = f2b(cs * xe - sn * xo);
    Q[o + 1] = f2b(sn * xe + cs * xo);
  }
  {
    float xe = b2f(K[o]), xo = b2f(K[o + 1]);
    K[o]     = f2b(cs * xe - sn * xo);
    K[o + 1] = f2b(sn * xe + cs * xo);
  }
}

// ---------------------------------------------------------------- C = A * B^T
// 128xBN tile, BK=32, 256 threads = 4 waves in 2x2; BN=128: wave 64x64 (4x4),
// BN=64: wave 64x32 (4x2). BN=64 doubles block count for small-N GEMMs.
template <int BN>
__global__ __launch_bounds__(256) void k_gemm_bt(
    const u16* __restrict__ A,
    const u16* __restrict__ B0, const u16* __restrict__ B1, const u16* __restrict__ B2,
    u16* __restrict__ O0, u16* __restrict__ O1, u16* __restrict__ O2,
    float* __restrict__ OF, int M, int N, int K, int f32out) {
  constexpr int NFR = BN / 32;            // n-frags per wave
  __shared__ __align__(16) u16 lsA[128 * 32];
  __shared__ __align__(16) u16 lsB[BN * 32];
  const int tid = threadIdx.x, lane = tid & 63, wave = tid >> 6;
  const int quad = lane >> 4, l16 = lane & 15;
  const int wrow = wave >> 1, wcol = wave & 1;
  const int m0 = blockIdx.x * 128, n0 = blockIdx.y * BN;
  const int z = blockIdx.z;
  const u16* Bp = (z == 0) ? B0 : (z == 1) ? B1 : B2;
  u16* Op = (z == 0) ? O0 : (z == 1) ? O1 : O2;
  f32x4 acc[4][NFR] = {};

  for (int k0 = 0; k0 < K; k0 += 32) {
#pragma unroll
    for (int c = 0; c < 2; ++c) {
      int f = (wave * 2 + c) * 512 + lane * 8;
      int row = f >> 5, colk = f & 31;
      GLDS(A + (size_t)(m0 + row) * K + k0 + colk, lsA + (wave * 2 + c) * 512);
    }
#pragma unroll
    for (int c = 0; c < BN / 64; ++c) {
      int cc = wave * (BN / 64) + c;
      int f = cc * 512 + lane * 8;
      int row = f >> 5, colk = f & 31;
      GLDS(Bp + (size_t)(n0 + row) * K + k0 + colk, lsB + cc * 512);
    }
    __syncthreads();
    s16x8 af[4], bfr[NFR];
#pragma unroll
    for (int i = 0; i < 4; ++i)
      af[i] = *reinterpret_cast<const s16x8*>(&lsA[(wrow * 64 + i * 16 + l16) * 32 + quad * 8]);
#pragma unroll
    for (int i = 0; i < NFR; ++i)
      bfr[i] = *reinterpret_cast<const s16x8*>(&lsB[(wcol * (BN / 2) + i * 16 + l16) * 32 + quad * 8]);
#pragma unroll
    for (int mi = 0; mi < 4; ++mi)
#pragma unroll
      for (int ni = 0; ni < NFR; ++ni)
        acc[mi][ni] = __builtin_amdgcn_mfma_f32_16x16x32_bf16(af[mi], bfr[ni], acc[mi][ni], 0, 0, 0);
    __syncthreads();
  }

#pragma unroll
  for (int mi = 0; mi < 4; ++mi)
#pragma unroll
    for (int ni = 0; ni < NFR; ++ni)
#pragma unroll
      for (int r = 0; r < 4; ++r) {
        int row = m0 + wrow * 64 + mi * 16 + quad * 4 + r;
        int col = n0 + wcol * (BN / 2) + ni * 16 + l16;
        float v = acc[mi][ni][r];
        size_t idx = (size_t)row * N + col;
        if (f32out) OF[idx] = v;
        else        Op[idx] = f2b(v);
      }
}

// ---------------------------------------------------------------- flash attention (causal)
// 1-D grid of 1024: qt = bid>>5 (so co-resident blocks per CU mix short/long
// causal strips), bh = bid&31. 4 waves, wave owns 16 q rows; k-tiles of 64.
__global__ __launch_bounds__(256) void k_flash(const u16* __restrict__ Q,
                                               const u16* __restrict__ K,
                                               const u16* __restrict__ V,
                                               u16* __restrict__ O) {
  __shared__ __align__(16) u16 lsK[64 * 64];       // [key][dk], swizzled
  __shared__ __align__(16) u16 lsVT[64 * 64];      // [dk][key], swizzled
  __shared__ __align__(16) u16 lsP[4][16 * 64];    // per-wave P, swizzled
  const int tid = threadIdx.x, lane = tid & 63, wave = tid >> 6;
  const int quad = lane >> 4, l16 = lane & 15;
  const int bid = blockIdx.x;
  const int bh = bid & 31;
  const int h = bh & (H_ - 1), b = bh >> 4;
  const int q0 = (bid >> 5) * 64;
  const int qrow = q0 + wave * 16;

  // Q A-frags from global, pre-scaled by 1/sqrt(dk) (exact in bf16)
  const size_t qoff = (size_t)(b * Ss + qrow + l16) * Dm + h * 64;
  s16x8 qf0 = *reinterpret_cast<const s16x8*>(&Q[qoff + quad * 8]);
  s16x8 qf1 = *reinterpret_cast<const s16x8*>(&Q[qoff + 32 + quad * 8]);
#pragma unroll
  for (int j = 0; j < 8; ++j) {
    qf0[j] = (short)f2b(b2f((u16)qf0[j]) * 0.125f);
    qf1[j] = (short)f2b(b2f((u16)qf1[j]) * 0.125f);
  }
  s16x8 ones;
#pragma unroll
  for (int j = 0; j < 8; ++j) ones[j] = (short)0x3F80;   // bf16 1.0

  f32x4 o[4] = {};
  f32x4 lAcc = {};                                        // row-sums via MFMA
  float m_i[4], alpha[4];
#pragma unroll
  for (int r = 0; r < 4; ++r) m_i[r] = -INFINITY;
  const int ktmax = q0 >> 6;
  const int c0 = wave * 2;

  for (int kt = 0; kt <= ktmax; ++kt) {
    const size_t kvbase = (size_t)(b * Ss + kt * 64) * Dm + h * 64;
    // stage K tile [64][64] swizzled: permute SOURCE columns so the fixed
    // lane->LDS mapping lands data at SW64 positions
#pragma unroll
    for (int c = 0; c < 2; ++c) {
      int slot = (c0 + c) * 64 + lane;        // 16B chunk slot
      int row = slot >> 3;
      int g = ((slot & 7) ^ (row & 7) ^ (row >> 3)) & 7;
      GLDS(K + kvbase + (size_t)row * Dm + g * 8, lsK + (c0 + c) * 512);
    }
    // stage V transposed: lsVT[dk][key], swizzled scalar stores
#pragma unroll
    for (int it = 0; it < 2; ++it) {
      int r  = (tid >> 3) + it * 32;
      int cv = (tid & 7) * 8;
      s16x8 vv = *reinterpret_cast<const s16x8*>(&V[kvbase + (size_t)r * Dm + cv]);
#pragma unroll
      for (int j = 0; j < 8; ++j) lsVT[SW64(cv + j, r)] = (u16)vv[j];
    }
    __syncthreads();

    // S = Q K^T
    f32x4 s[4] = {};
#pragma unroll
    for (int ni = 0; ni < 4; ++ni) {
      s16x8 kf0 = *reinterpret_cast<const s16x8*>(&lsK[SW64(ni * 16 + l16, quad * 8)]);
      s16x8 kf1 = *reinterpret_cast<const s16x8*>(&lsK[SW64(ni * 16 + l16, 32 + quad * 8)]);
      s[ni] = __builtin_amdgcn_mfma_f32_16x16x32_bf16(qf0, kf0, s[ni], 0, 0, 0);
      s[ni] = __builtin_amdgcn_mfma_f32_16x16x32_bf16(qf1, kf1, s[ni], 0, 0, 0);
    }
    if (kt == ktmax) {   // causal mask on diagonal tile
#pragma unroll
      for (int ni = 0; ni < 4; ++ni)
#pragma unroll
        for (int r = 0; r < 4; ++r) {
          int gq = qrow + quad * 4 + r;
          int gk = kt * 64 + ni * 16 + l16;
          if (gk > gq) s[ni][r] = -INFINITY;
        }
    }

    // online softmax: only the MAX needs a cross-lane reduce (l via MFMA)
#pragma unroll
    for (int r = 0; r < 4; ++r) {
      float mx = fmaxf(fmaxf(s[0][r], s[1][r]), fmaxf(s[2][r], s[3][r]));
#pragma unroll
      for (int off = 8; off >= 1; off >>= 1) mx = fmaxf(mx, __shfl_xor(mx, off, 16));
      float mnew = fmaxf(m_i[r], mx);
      alpha[r] = __expf(m_i[r] - mnew);
      m_i[r] = mnew;
#pragma unroll
      for (int ni = 0; ni < 4; ++ni) s[ni][r] = __expf(s[ni][r] - mnew);
    }
    // rescale accumulators, write P (C-layout -> LDS -> A-layout)
#pragma unroll
    for (int ni = 0; ni < 4; ++ni)
#pragma unroll
      for (int r = 0; r < 4; ++r) {
        o[ni][r] *= alpha[r];
        lsP[wave][SW64(quad * 4 + r, ni * 16 + l16)] = f2b(s[ni][r]);
      }
#pragma unroll
    for (int r = 0; r < 4; ++r) lAcc[r] *= alpha[r];

    // O += P V ; l += P 1  (ones B-frag reuses pf)
#pragma unroll
    for (int kc = 0; kc < 2; ++kc) {
      s16x8 pf = *reinterpret_cast<const s16x8*>(&lsP[wave][SW64(l16, kc * 32 + quad * 8)]);
      lAcc = __builtin_amdgcn_mfma_f32_16x16x32_bf16(pf, ones, lAcc, 0, 0, 0);
#pragma unroll
      for (int ni = 0; ni < 4; ++ni) {
        s16x8 vf = *reinterpret_cast<const s16x8*>(&lsVT[SW64(ni * 16 + l16, kc * 32 + quad * 8)]);
        o[ni] = __builtin_amdgcn_mfma_f32_16x16x32_bf16(pf, vf, o[ni], 0, 0, 0);
      }
    }
    __syncthreads();
  }

#pragma unroll
  for (int ni = 0; ni < 4; ++ni)
#pragma unroll
    for (int r = 0; r < 4; ++r) {
      int gq = qrow + quad * 4 + r;
      int gc = h * 64 + ni * 16 + l16;
      O[(size_t)(b * Ss + gq) * Dm + gc] = f2b(o[ni][r] / lAcc[r]);
    }
}

// ---------------------------------------------------------------- launch
extern "C" void kernel_launch(void* const* d_in, const int* in_sizes, int n_in,
                              void* d_out, int out_size, void* d_ws, size_t ws_size,
                              hipStream_t stream) {
  const float* x  = (const float*)d_in[0];
  const float* Wq = (const float*)d_in[1];
  const float* Wk = (const float*)d_in[2];
  const float* Wv = (const float*)d_in[3];
  const float* Wo = (const float*)d_in[4];
  const int* pos  = (const int*)d_in[5];
  float* out = (float*)d_out;

  char* w = (char*)d_ws;
  u16* xb  = (u16*)w; w += (size_t)Mrows * Dm * 2;
  u16* wqb = (u16*)w; w += (size_t)Dm * Dm * 2;
  u16* wkb = (u16*)w; w += (size_t)Dm * Dm * 2;
  u16* wvb = (u16*)w; w += (size_t)Dm * Dm * 2;
  u16* wob = (u16*)w; w += (size_t)Dm * Dm * 2;
  u16* Qb  = (u16*)w; w += (size_t)Mrows * Dm * 2;
  u16* Kb  = (u16*)w; w += (size_t)Mrows * Dm * 2;
  u16* Vb  = (u16*)w; w += (size_t)Mrows * Dm * 2;
  u16* Ab  = (u16*)w; w += (size_t)Mrows * Dm * 2;

  k_cast<<<(Mrows * Dm / 4 + 255) / 256, 256, 0, stream>>>(x, xb, Mrows * Dm / 4);
  k_cast<<<(Dm * Dm / 4 + 255) / 256, 256, 0, stream>>>(Wq, wqb, Dm * Dm / 4);
  k_cast<<<(Dm * Dm / 4 + 255) / 256, 256, 0, stream>>>(Wk, wkb, Dm * Dm / 4);
  k_cast<<<(Dm * Dm / 4 + 255) / 256, 256, 0, stream>>>(Wv, wvb, Dm * Dm / 4);
  k_cast<<<(Dm * Dm / 4 + 255) / 256, 256, 0, stream>>>(Wo, wob, Dm * Dm / 4);

  // fused QKV projections: z selects W and destination (768 blocks, 3/CU)
  k_gemm_bt<128><<<dim3(32, 8, 3), 256, 0, stream>>>(xb, wqb, wkb, wvb,
                                                     Qb, Kb, Vb, nullptr,
                                                     Mrows, Dm, Dm, 0);
  k_rope<<<(Mrows * 512 + 255) / 256, 256, 0, stream>>>(Qb, Kb, pos);
  k_flash<<<dim3(1024), 256, 0, stream>>>(Qb, Kb, Vb, Ab);
  // output projection, fp32 epilogue; BN=64 -> 512 blocks (2/CU)
  k_gemm_bt<64><<<dim3(32, 16, 1), 256, 0, stream>>>(Ab, wob, wob, wob,
                                                     nullptr, nullptr, nullptr, out,
                                                     Mrows, Dm, Dm, 1);
}

// Round 3
// 214.828 us; speedup vs baseline: 1.7143x; 1.2103x over previous
//
#include <hip/hip_runtime.h>
#include <hip/hip_bf16.h>
#include <math.h>

#define H_    16
#define DK_   64
#define Dm    1024
#define Bb    2
#define Ss    2048
#define Mrows 4096   // B*S

typedef short s16x8 __attribute__((ext_vector_type(8)));
typedef float f32x4 __attribute__((ext_vector_type(4)));
typedef unsigned short u16;

__device__ __forceinline__ u16 f2b(float f) {
  __hip_bfloat16 h = __float2bfloat16(f);
  return *reinterpret_cast<u16*>(&h);
}
__device__ __forceinline__ float b2f(u16 u) {
  __hip_bfloat16 h;
  *reinterpret_cast<u16*>(&h) = u;
  return __bfloat162float(h);
}

// async global->LDS, 16B per lane; LDS dest = wave-uniform base + lane*16
#define GLDS(g, l)                                                             \
  __builtin_amdgcn_global_load_lds(                                            \
      (const __attribute__((address_space(1))) unsigned int*)(g),              \
      (__attribute__((address_space(3))) unsigned int*)(l), 16, 0, 0)

// XOR-swizzle for [rows][64] u16 tiles, 16B-chunk granular
__device__ __forceinline__ int SW64(int row, int col) {
  return row * 64 + ((((col >> 3) ^ (row & 7) ^ (row >> 3)) & 7) << 3) + (col & 7);
}

// ---------------------------------------------------------------- casts fp32->bf16
__global__ __launch_bounds__(256) void k_cast(const float* __restrict__ s,
                                              u16* __restrict__ d, int n4) {
  int i = blockIdx.x * 256 + threadIdx.x;
  if (i >= n4) return;
  float4 v = reinterpret_cast<const float4*>(s)[i];
  ushort4 o;
  o.x = f2b(v.x); o.y = f2b(v.y); o.z = f2b(v.z); o.w = f2b(v.w);
  reinterpret_cast<ushort4*>(d)[i] = o;
}

__global__ __launch_bounds__(256) void k_cast4(const float* __restrict__ s0, const float* __restrict__ s1,
                                               const float* __restrict__ s2, const float* __restrict__ s3,
                                               u16* __restrict__ d0, u16* __restrict__ d1,
                                               u16* __restrict__ d2, u16* __restrict__ d3) {
  int y = blockIdx.y;
  const float* s = (y == 0) ? s0 : (y == 1) ? s1 : (y == 2) ? s2 : s3;
  u16* d = (y == 0) ? d0 : (y == 1) ? d1 : (y == 2) ? d2 : d3;
  int i = blockIdx.x * 256 + threadIdx.x;
  float4 v = reinterpret_cast<const float4*>(s)[i];
  ushort4 o;
  o.x = f2b(v.x); o.y = f2b(v.y); o.z = f2b(v.z); o.w = f2b(v.w);
  reinterpret_cast<ushort4*>(d)[i] = o;
}

// ---------------------------------------------------------------- RoPE on Q and K (bf16 in/out)
__global__ __launch_bounds__(256) void k_rope(u16* __restrict__ Q, u16* __restrict__ K,
                                              const int* __restrict__ pos) {
  int idx = blockIdx.x * 256 + threadIdx.x;
  if (idx >= Mrows * (Dm / 2)) return;
  int row = idx >> 9;
  int pc  = idx & 511;
  int i   = pc & 31;       // pair index within head (d2 = 32)
  int h   = pc >> 5;
  int col = h * 64 + i * 2;
  float p   = (float)pos[row & (Ss - 1)];
  float inv = powf(10000.0f, -(float)i / 32.0f);
  float ang = p * inv;
  float sn = sinf(ang), cs = cosf(ang);
  size_t o = (size_t)row * Dm + col;
  {
    float xe = b2f(Q[o]), xo = b2f(Q[o + 1]);
    Q[o]     = f2b(cs * xe - sn * xo);
    Q[o + 1] = f2b(sn * xe + cs * xo);
  }
  {
    float xe = b2f(K[o]), xo = b2f(K[o + 1]);
    K[o]     = f2b(cs * xe - sn * xo);
    K[o + 1] = f2b(sn * xe + cs * xo);
  }
}

// ---------------------------------------------------------------- C = A * B^T
// 128xBN tile, BK=32, 256 threads = 4 waves in 2x2. z==2 writes V TRANSPOSED
// to OVT[b][e][s] (packed 8B stores; each 128B line fully covered in-block).
template <int BN>
__global__ __launch_bounds__(256) void k_gemm_bt(
    const u16* __restrict__ A,
    const u16* __restrict__ B0, const u16* __restrict__ B1, const u16* __restrict__ B2,
    u16* __restrict__ O0, u16* __restrict__ O1, u16* __restrict__ OVT,
    float* __restrict__ OF, int M, int N, int K, int f32out) {
  constexpr int NFR = BN / 32;
  __shared__ __align__(16) u16 lsA[128 * 32];
  __shared__ __align__(16) u16 lsB[BN * 32];
  const int tid = threadIdx.x, lane = tid & 63, wave = tid >> 6;
  const int quad = lane >> 4, l16 = lane & 15;
  const int wrow = wave >> 1, wcol = wave & 1;
  const int m0 = blockIdx.x * 128, n0 = blockIdx.y * BN;
  const int z = blockIdx.z;
  const u16* Bp = (z == 0) ? B0 : (z == 1) ? B1 : B2;
  u16* Op = (z == 0) ? O0 : O1;
  f32x4 acc[4][NFR] = {};

  for (int k0 = 0; k0 < K; k0 += 32) {
#pragma unroll
    for (int c = 0; c < 2; ++c) {
      int f = (wave * 2 + c) * 512 + lane * 8;
      int row = f >> 5, colk = f & 31;
      GLDS(A + (size_t)(m0 + row) * K + k0 + colk, lsA + (wave * 2 + c) * 512);
    }
#pragma unroll
    for (int c = 0; c < BN / 64; ++c) {
      int cc = wave * (BN / 64) + c;
      int f = cc * 512 + lane * 8;
      int row = f >> 5, colk = f & 31;
      GLDS(Bp + (size_t)(n0 + row) * K + k0 + colk, lsB + cc * 512);
    }
    __syncthreads();
    s16x8 af[4], bfr[NFR];
#pragma unroll
    for (int i = 0; i < 4; ++i)
      af[i] = *reinterpret_cast<const s16x8*>(&lsA[(wrow * 64 + i * 16 + l16) * 32 + quad * 8]);
#pragma unroll
    for (int i = 0; i < NFR; ++i)
      bfr[i] = *reinterpret_cast<const s16x8*>(&lsB[(wcol * (BN / 2) + i * 16 + l16) * 32 + quad * 8]);
#pragma unroll
    for (int mi = 0; mi < 4; ++mi)
#pragma unroll
      for (int ni = 0; ni < NFR; ++ni)
        acc[mi][ni] = __builtin_amdgcn_mfma_f32_16x16x32_bf16(af[mi], bfr[ni], acc[mi][ni], 0, 0, 0);
    __syncthreads();
  }

  if (!f32out && z == 2) {
    // transposed V epilogue: VT[b][e][s], 4 consecutive s per lane -> 8B store
#pragma unroll
    for (int mi = 0; mi < 4; ++mi)
#pragma unroll
      for (int ni = 0; ni < NFR; ++ni) {
        int row0 = m0 + wrow * 64 + mi * 16 + quad * 4;
        int col  = n0 + wcol * (BN / 2) + ni * 16 + l16;
        int bb = row0 >> 11, s0 = row0 & (Ss - 1);
        ushort4 pk;
        pk.x = f2b(acc[mi][ni][0]); pk.y = f2b(acc[mi][ni][1]);
        pk.z = f2b(acc[mi][ni][2]); pk.w = f2b(acc[mi][ni][3]);
        *reinterpret_cast<ushort4*>(&OVT[((size_t)bb * Dm + col) * Ss + s0]) = pk;
      }
    return;
  }
#pragma unroll
  for (int mi = 0; mi < 4; ++mi)
#pragma unroll
    for (int ni = 0; ni < NFR; ++ni)
#pragma unroll
      for (int r = 0; r < 4; ++r) {
        int row = m0 + wrow * 64 + mi * 16 + quad * 4 + r;
        int col = n0 + wcol * (BN / 2) + ni * 16 + l16;
        float v = acc[mi][ni][r];
        size_t idx = (size_t)row * N + col;
        if (f32out) OF[idx] = v;
        else        Op[idx] = f2b(v);
      }
}

// ---------------------------------------------------------------- flash attention (causal)
// Transposed-compute formulation: S^T = K Q^T (mfma(kf,qf)), O^T = V^T P^T
// (mfma(vf,pf)). Softmax state is per-lane scalar (q = lane&15); P^T packs
// to b64 LDS stores; V^T staged directly from pre-transposed global VT.
__global__ __launch_bounds__(256) void k_flash(const u16* __restrict__ Q,
                                               const u16* __restrict__ K,
                                               const u16* __restrict__ VT,
                                               u16* __restrict__ O) {
  __shared__ __align__(16) u16 lsK[64 * 64];       // [key][dk], SW64
  __shared__ __align__(16) u16 lsVT[64 * 64];      // [dk][key], SW64
  __shared__ __align__(16) u16 lsP[4][16 * 64];    // per-wave P [q][key], chunk-xor
  const int tid = threadIdx.x, lane = tid & 63, wave = tid >> 6;
  const int quad = lane >> 4, l16 = lane & 15;
  const int bid = blockIdx.x;
  const int bh = bid & 31;
  const int h = bh & (H_ - 1), b = bh >> 4;
  const int q0 = (bid >> 5) * 64;
  const int qrow = q0 + wave * 16;
  const int xorv = (l16 * 2) & 0xE;                // even 8B-chunk xor per q-row

  // Q frags (row = q = l16, k-contig dk), pre-scaled by 1/sqrt(dk)
  const size_t qoff = (size_t)(b * Ss + qrow + l16) * Dm + h * 64;
  s16x8 qf0 = *reinterpret_cast<const s16x8*>(&Q[qoff + quad * 8]);
  s16x8 qf1 = *reinterpret_cast<const s16x8*>(&Q[qoff + 32 + quad * 8]);
#pragma unroll
  for (int j = 0; j < 8; ++j) {
    qf0[j] = (short)f2b(b2f((u16)qf0[j]) * 0.125f);
    qf1[j] = (short)f2b(b2f((u16)qf1[j]) * 0.125f);
  }

  f32x4 ot[4] = {};          // O^T frags: row=dk=ni*16+quad*4+r, col=q=l16
  float m_i = -INFINITY, l_i = 0.f;
  const int ktmax = q0 >> 6;
  const int c0 = wave * 2;

  for (int kt = 0; kt <= ktmax; ++kt) {
    const size_t kbase  = (size_t)(b * Ss + kt * 64) * Dm + h * 64;
    const size_t vtbase = ((size_t)b * Dm + h * 64) * Ss + kt * 64;
    // stage K [key][dk] and V^T [dk][key], source-permuted for SW64 layout
#pragma unroll
    for (int c = 0; c < 2; ++c) {
      int slot = (c0 + c) * 64 + lane;
      int row = slot >> 3;
      int g = ((slot & 7) ^ (row & 7) ^ (row >> 3)) & 7;
      GLDS(K  + kbase  + (size_t)row * Dm + g * 8, lsK  + (c0 + c) * 512);
      GLDS(VT + vtbase + (size_t)row * Ss + g * 8, lsVT + (c0 + c) * 512);
    }
    __syncthreads();

    // S^T = K Q^T : D[m=key][n=q]
    f32x4 st[4] = {};
#pragma unroll
    for (int kc = 0; kc < 2; ++kc) {
      s16x8 qf = kc ? qf1 : qf0;
#pragma unroll
      for (int ni = 0; ni < 4; ++ni) {
        s16x8 kf = *reinterpret_cast<const s16x8*>(&lsK[SW64(ni * 16 + l16, kc * 32 + quad * 8)]);
        st[ni] = __builtin_amdgcn_mfma_f32_16x16x32_bf16(kf, qf, st[ni], 0, 0, 0);
      }
    }
    if (kt == ktmax) {   // causal mask: key > q
      int gq = qrow + l16;
#pragma unroll
      for (int ni = 0; ni < 4; ++ni)
#pragma unroll
        for (int r = 0; r < 4; ++r)
          if (kt * 64 + ni * 16 + quad * 4 + r > gq) st[ni][r] = -INFINITY;
    }

    // online softmax per q (= per lane): in-lane 16 vals + 2 cross-quad shfls
    float mx = -INFINITY;
#pragma unroll
    for (int ni = 0; ni < 4; ++ni)
#pragma unroll
      for (int r = 0; r < 4; ++r) mx = fmaxf(mx, st[ni][r]);
    mx = fmaxf(mx, __shfl_xor(mx, 16));
    mx = fmaxf(mx, __shfl_xor(mx, 32));
    float mnew = fmaxf(m_i, mx);
    float alpha = __expf(m_i - mnew);
    m_i = mnew;
    float rs = 0.f;
#pragma unroll
    for (int ni = 0; ni < 4; ++ni)
#pragma unroll
      for (int r = 0; r < 4; ++r) {
        float p = __expf(st[ni][r] - mnew);
        st[ni][r] = p;
        rs += p;
      }
    rs += __shfl_xor(rs, 16);
    rs += __shfl_xor(rs, 32);
    l_i = l_i * alpha + rs;
#pragma unroll
    for (int ni = 0; ni < 4; ++ni) ot[ni] *= alpha;

    // P^T -> lsP[q][key]: 4 consecutive keys per lane -> one b64 store
#pragma unroll
    for (int ni = 0; ni < 4; ++ni) {
      ushort4 pk;
      pk.x = f2b(st[ni][0]); pk.y = f2b(st[ni][1]);
      pk.z = f2b(st[ni][2]); pk.w = f2b(st[ni][3]);
      *reinterpret_cast<ushort4*>(&lsP[wave][l16 * 64 + (((ni * 4 + quad) ^ xorv) << 2)]) = pk;
    }
    // O^T += V^T P^T
#pragma unroll
    for (int kc = 0; kc < 2; ++kc) {
      s16x8 pf = *reinterpret_cast<const s16x8*>(
          &lsP[wave][l16 * 64 + ((((kc * 8 + quad * 2)) ^ xorv) << 2)]);
#pragma unroll
      for (int ni = 0; ni < 4; ++ni) {
        s16x8 vf = *reinterpret_cast<const s16x8*>(&lsVT[SW64(ni * 16 + l16, kc * 32 + quad * 8)]);
        ot[ni] = __builtin_amdgcn_mfma_f32_16x16x32_bf16(vf, pf, ot[ni], 0, 0, 0);
      }
    }
    __syncthreads();
  }

  // epilogue: O[q][dk], 4 consecutive dk per lane -> 8B stores
  float inv = 1.0f / l_i;
  const size_t obase = (size_t)(b * Ss + qrow + l16) * Dm + h * 64;
#pragma unroll
  for (int ni = 0; ni < 4; ++ni) {
    ushort4 pk;
    pk.x = f2b(ot[ni][0] * inv); pk.y = f2b(ot[ni][1] * inv);
    pk.z = f2b(ot[ni][2] * inv); pk.w = f2b(ot[ni][3] * inv);
    *reinterpret_cast<ushort4*>(&O[obase + ni * 16 + quad * 4]) = pk;
  }
}

// ---------------------------------------------------------------- launch
extern "C" void kernel_launch(void* const* d_in, const int* in_sizes, int n_in,
                              void* d_out, int out_size, void* d_ws, size_t ws_size,
                              hipStream_t stream) {
  const float* x  = (const float*)d_in[0];
  const float* Wq = (const float*)d_in[1];
  const float* Wk = (const float*)d_in[2];
  const float* Wv = (const float*)d_in[3];
  const float* Wo = (const float*)d_in[4];
  const int* pos  = (const int*)d_in[5];
  float* out = (float*)d_out;

  char* w = (char*)d_ws;
  u16* xb  = (u16*)w; w += (size_t)Mrows * Dm * 2;
  u16* wqb = (u16*)w; w += (size_t)Dm * Dm * 2;
  u16* wkb = (u16*)w; w += (size_t)Dm * Dm * 2;
  u16* wvb = (u16*)w; w += (size_t)Dm * Dm * 2;
  u16* wob = (u16*)w; w += (size_t)Dm * Dm * 2;
  u16* Qb  = (u16*)w; w += (size_t)Mrows * Dm * 2;
  u16* Kb  = (u16*)w; w += (size_t)Mrows * Dm * 2;
  u16* VTb = (u16*)w; w += (size_t)Mrows * Dm * 2;   // V transposed [b][e][s]
  u16* Ab  = (u16*)w; w += (size_t)Mrows * Dm * 2;

  k_cast<<<Mrows * Dm / 1024, 256, 0, stream>>>(x, xb, Mrows * Dm / 4);
  k_cast4<<<dim3(Dm * Dm / 1024, 4), 256, 0, stream>>>(Wq, Wk, Wv, Wo, wqb, wkb, wvb, wob);

  // fused QKV projections; z==2 writes V transposed to VTb
  k_gemm_bt<128><<<dim3(32, 8, 3), 256, 0, stream>>>(xb, wqb, wkb, wvb,
                                                     Qb, Kb, VTb, nullptr,
                                                     Mrows, Dm, Dm, 0);
  k_rope<<<(Mrows * 512) / 256, 256, 0, stream>>>(Qb, Kb, pos);
  k_flash<<<dim3(1024), 256, 0, stream>>>(Qb, Kb, VTb, Ab);
  // output projection, fp32 epilogue; BN=64 -> 512 blocks
  k_gemm_bt<64><<<dim3(32, 16, 1), 256, 0, stream>>>(Ab, wob, wob, wob,
                                                     nullptr, nullptr, nullptr, out,
                                                     Mrows, Dm, Dm, 1);
}